// Round 1
// baseline (373.591 us; speedup 1.0000x reference)
//
#include <hip/hip_runtime.h>
#include <math.h>

#define Bq 4
#define Hq 512
#define Nq 64
#define Lq 2048
#define PARAM (Hq*Nq)   // 32768
#define BH   (Bq*Hq)    // 2048
#define CCH  4          // L-chunks for the two-pass parallel scan
#define LC   (Lq/CCH)   // 512
static_assert(Lq == CCH*LC, "chunking");

// ---------------------------------------------------------------------------
// Phase 1: per-(h,n) parameter prep.
//   w  = exp(dt*A)                (complex, A = -exp(log_A_real) + i*A_imag)
//   dB = B * (w-1)/A
//   CB = C * dB ;  store a = 2*Re(CB), b = -2*Im(CB) so y += a*sr + b*si
//   Also w^(j*LC) for j=1..CCH-1 (chunk-combine powers), via repeated
//   squaring of the *fp32* w in double so it matches the sequential product.
// ---------------------------------------------------------------------------
__global__ void prep_kernel(const float* __restrict__ log_dt,
                            const float* __restrict__ log_A_real,
                            const float* __restrict__ A_imag,
                            const float* __restrict__ B_re, const float* __restrict__ B_im,
                            const float* __restrict__ C_re, const float* __restrict__ C_im,
                            float* __restrict__ wr_, float* __restrict__ wi_,
                            float* __restrict__ a0, float* __restrict__ b0,
                            float* __restrict__ a1, float* __restrict__ b1,
                            float* __restrict__ wpr, float* __restrict__ wpi) {
    int idx = blockIdx.x * blockDim.x + threadIdx.x;
    if (idx >= PARAM) return;
    int h = idx >> 6;            // idx / Nq
    float dt = expf(log_dt[h]);
    float Ar = -expf(log_A_real[idx]);
    float Ai = A_imag[idx];
    float er = expf(Ar * dt);
    float wr = er * cosf(Ai * dt);
    float wi = er * sinf(Ai * dt);
    wr_[idx] = wr; wi_[idx] = wi;
    // (w-1)/A
    float mr = wr - 1.0f, mi = wi;
    float den = Ar * Ar + Ai * Ai;
    float qr = (mr * Ar + mi * Ai) / den;
    float qi = (mi * Ar - mr * Ai) / den;
    float Br = B_re[idx], Bi = B_im[idx];
    float dBr = Br * qr - Bi * qi;
    float dBi = Br * qi + Bi * qr;
    // dir 0
    float cr = C_re[idx], ci = C_im[idx];
    a0[idx] =  2.0f * (cr * dBr - ci * dBi);
    b0[idx] = -2.0f * (cr * dBi + ci * dBr);
    // dir 1
    cr = C_re[PARAM + idx]; ci = C_im[PARAM + idx];
    a1[idx] =  2.0f * (cr * dBr - ci * dBi);
    b1[idx] = -2.0f * (cr * dBi + ci * dBr);
    // w^LC by 9 squarings (LC = 512 = 2^9), double precision
    double pr = (double)wr, pq = (double)wi;
    #pragma unroll
    for (int s = 0; s < 9; ++s) {
        double nr = pr*pr - pq*pq;
        double ni = 2.0*pr*pq;
        pr = nr; pq = ni;
    }
    wpr[idx] = (float)pr;  wpi[idx] = (float)pq;                    // w^512
    double p2r = pr*pr - pq*pq, p2i = 2.0*pr*pq;
    wpr[PARAM + idx] = (float)p2r; wpi[PARAM + idx] = (float)p2i;   // w^1024
    double p3r = p2r*pr - p2i*pq, p3i = p2r*pq + p2i*pr;
    wpr[2*PARAM + idx] = (float)p3r; wpi[2*PARAM + idx] = (float)p3i; // w^1536
}

// ---------------------------------------------------------------------------
// Phase 2: LayerNorm over channel dim H for each (b,l).  (unchanged)
// ---------------------------------------------------------------------------
__global__ __launch_bounds__(256)
void ln_kernel(const float* __restrict__ x, const float* __restrict__ lnw,
               const float* __restrict__ lnb, float* __restrict__ z) {
    int blk = blockIdx.x;
    int b  = blk / (Lq / 16);
    int l0 = (blk % (Lq / 16)) * 16;
    int tx = threadIdx.x & 15;   // l within tile
    int ty = threadIdx.x >> 4;   // h group
    const float* xb = x + (size_t)b * Hq * Lq;
    float s = 0.f, s2 = 0.f;
    for (int h = ty; h < Hq; h += 16) {
        float v = xb[h * Lq + l0 + tx];
        s += v; s2 += v * v;
    }
    __shared__ float rs_[16][17], r2_[16][17], mu_s[16], sg_s[16];
    rs_[ty][tx] = s; r2_[ty][tx] = s2;
    __syncthreads();
    if (ty == 0) {
        float a = 0.f, c = 0.f;
        #pragma unroll
        for (int i = 0; i < 16; ++i) { a += rs_[i][tx]; c += r2_[i][tx]; }
        float mu = a * (1.0f / Hq);
        float var = c * (1.0f / Hq) - mu * mu;
        mu_s[tx] = mu;
        sg_s[tx] = rsqrtf(var + 1e-5f);
    }
    __syncthreads();
    float mu = mu_s[tx], rs = sg_s[tx];
    float* zb = z + (size_t)b * Hq * Lq;
    for (int h = ty; h < Hq; h += 16) {
        float v = xb[h * Lq + l0 + tx];
        zb[h * Lq + l0 + tx] = (v - mu) * rs * lnw[h] + lnb[h];
    }
}

// ---------------------------------------------------------------------------
// SSM scan, two-pass chunked decomposition.
// tau is the scan-order index: dir 0 -> z[tau], dir 1 -> z[L-1-tau].
// Chunk c covers tau in [c*LC, (c+1)*LC).
// ---------------------------------------------------------------------------
__device__ __forceinline__ void sstep(float& sr, float& si, float wr, float wi, float zt) {
    float t1 = fmaf(wi, si, -zt);   // wi*si - z
    float t2 = wi * sr;
    sr = fmaf(wr, sr, -t1);         // wr*sr - wi*si + z
    si = fmaf(wr, si, t2);
}

#define SSTEP4(qq)  do { sstep(sr,si,wr,wi,(qq).x); sstep(sr,si,wr,wi,(qq).y); \
                         sstep(sr,si,wr,wi,(qq).z); sstep(sr,si,wr,wi,(qq).w); } while(0)
#define SSTEP4R(qq) do { sstep(sr,si,wr,wi,(qq).w); sstep(sr,si,wr,wi,(qq).z); \
                         sstep(sr,si,wr,wi,(qq).y); sstep(sr,si,wr,wi,(qq).x); } while(0)

// Pass 1: chunk-local final states (chunks 0..CCH-2), zero init, no outputs.
// Block = 4 waves, each wave an independent (bh) instance. No LDS.
__global__ __launch_bounds__(256, 8)
void local_kernel(const float* __restrict__ z,
                  const float* __restrict__ wr_, const float* __restrict__ wi_,
                  float* __restrict__ slocal) {
    int wv = threadIdx.x >> 6;
    int n  = threadIdx.x & 63;
    int bh = blockIdx.x * 4 + wv;
    int dir = blockIdx.y;
    int c  = blockIdx.z;                    // 0..CCH-2
    int h  = bh & (Hq - 1);
    int pidx = h * Nq + n;
    float wr = wr_[pidx], wi = wi_[pidx];
    const float* zz = z + (size_t)bh * Lq;
    float sr = 0.f, si = 0.f;
    int tau0 = c * LC;
    if (dir == 0) {
        const float4* zp = (const float4*)(zz + tau0);
        for (int jj = 0; jj < LC; jj += 16) {
            float4 q0 = zp[0], q1 = zp[1], q2 = zp[2], q3 = zp[3];
            zp += 4;
            SSTEP4(q0); SSTEP4(q1); SSTEP4(q2); SSTEP4(q3);
        }
    } else {
        for (int jj = 0; jj < LC; jj += 16) {
            const float4* zp = (const float4*)(zz + Lq - tau0 - jj - 16);
            float4 q0 = zp[0], q1 = zp[1], q2 = zp[2], q3 = zp[3];
            SSTEP4R(q3); SSTEP4R(q2); SSTEP4R(q1); SSTEP4R(q0);
        }
    }
    float* out = slocal + ((size_t)(bh * 2 + dir) * (CCH - 1) + c) * 128;
    out[n] = sr; out[64 + n] = si;
}

// Pass 2: real scan with outputs. Block = 4 waves = the 4 chunks of one
// (bh,dir). Each wave owns a private [64][17] tile slice -> no barriers
// (wave lockstep + in-order DS give RAW safety within a wave).
template <int DIR>
__device__ __forceinline__ void scan3_body(const float* __restrict__ zz,
                                           float* __restrict__ yout,
                                           float wr, float wi, float a, float b,
                                           float sr, float si, int tau0, int n,
                                           float (*tile)[17]) {
    int g = n >> 4, tc = n & 15;
    for (int q0 = 0; q0 < LC; q0 += 16) {
        float4 q[4];
        if (DIR == 0) {
            const float4* zp = (const float4*)(zz + tau0 + q0);
            q[0] = zp[0]; q[1] = zp[1]; q[2] = zp[2]; q[3] = zp[3];
        } else {
            const float4* zp = (const float4*)(zz + Lq - tau0 - q0 - 16);
            q[0] = zp[0]; q[1] = zp[1]; q[2] = zp[2]; q[3] = zp[3];
        }
        #pragma unroll
        for (int j = 0; j < 16; ++j) {
            float zt;
            if (DIR == 0) {
                float4 qq = q[j >> 2];
                zt = (j&3)==0 ? qq.x : (j&3)==1 ? qq.y : (j&3)==2 ? qq.z : qq.w;
            } else {
                float4 qq = q[3 - (j >> 2)];
                zt = (j&3)==0 ? qq.w : (j&3)==1 ? qq.z : (j&3)==2 ? qq.y : qq.x;
            }
            float p;
            if (DIR == 0) { sstep(sr, si, wr, wi, zt); p = fmaf(a, sr, b * si); }
            else          { p = fmaf(a, sr, b * si); sstep(sr, si, wr, wi, zt); }
            tile[n][j] = p;
        }
        __builtin_amdgcn_wave_barrier();
        // column sums: 4 lanes per timestep column, 16 rows each, then 2 shfl
        float acc = 0.f;
        #pragma unroll
        for (int r = 0; r < 16; ++r) acc += tile[g * 16 + r][tc];
        acc += __shfl_xor(acc, 16, 64);
        acc += __shfl_xor(acc, 32, 64);
        if (n < 16) {
            int t = tau0 + q0 + n;
            yout[DIR ? (Lq - 1 - t) : t] = acc;
        }
        __builtin_amdgcn_wave_barrier();
    }
}

__global__ __launch_bounds__(256, 8)
void scan_kernel(const float* __restrict__ z,
                 const float* __restrict__ wr_, const float* __restrict__ wi_,
                 const float* __restrict__ a0, const float* __restrict__ b0,
                 const float* __restrict__ a1, const float* __restrict__ b1,
                 const float* __restrict__ wpr, const float* __restrict__ wpi,
                 const float* __restrict__ slocal,
                 float* __restrict__ y0, float* __restrict__ y1) {
    __shared__ float tile[4][64][17];       // 17408 B -> 8 blocks/CU
    int c = threadIdx.x >> 6;               // chunk = wave id
    int n = threadIdx.x & 63;
    int bh = blockIdx.x, dir = blockIdx.y;
    int h = bh & (Hq - 1);
    int pidx = h * Nq + n;
    float wr = wr_[pidx], wi = wi_[pidx];
    // combine chunk-local states into this chunk's true initial state
    float sr = 0.f, si = 0.f;
    const float* sl = slocal + (size_t)(bh * 2 + dir) * (CCH - 1) * 128;
    for (int cp = 0; cp < c; ++cp) {
        float lr = sl[cp * 128 + n], li = sl[cp * 128 + 64 + n];
        int j = c - 1 - cp;                 // power of w^LC needed
        if (j == 0) { sr += lr; si += li; }
        else {
            float pr = wpr[(j - 1) * PARAM + pidx];
            float pi = wpi[(j - 1) * PARAM + pidx];
            sr += pr * lr - pi * li;
            si += pr * li + pi * lr;
        }
    }
    int tau0 = c * LC;
    const float* zz = z + (size_t)bh * Lq;
    if (dir == 0)
        scan3_body<0>(zz, y0 + (size_t)bh * Lq, wr, wi, a0[pidx], b0[pidx],
                      sr, si, tau0, n, tile[c]);
    else
        scan3_body<1>(zz, y1 + (size_t)bh * Lq, wr, wi, a1[pidx], b1[pidx],
                      sr, si, tau0, n, tile[c]);
}

// ---------------------------------------------------------------------------
// Phase 4: u = gelu_tanh(y0 + y1 + D*z), written in-place into y0. (unchanged)
// ---------------------------------------------------------------------------
__global__ __launch_bounds__(256)
void act_kernel(float4* __restrict__ y0, const float4* __restrict__ y1,
                const float4* __restrict__ z, const float* __restrict__ D) {
    int i4 = blockIdx.x * 256 + threadIdx.x;       // B*H*L/4 = 1048576
    int h = (i4 >> 9) & (Hq - 1);                  // (i4*4 / L) % H
    float d = D[h];
    float4 v0 = y0[i4], v1 = y1[i4], vz = z[i4];
    float vv[4] = { v0.x + v1.x + d * vz.x, v0.y + v1.y + d * vz.y,
                    v0.z + v1.z + d * vz.z, v0.w + v1.w + d * vz.w };
    #pragma unroll
    for (int i = 0; i < 4; ++i) {
        float v = vv[i];
        float t = tanhf(0.7978845608028654f * (v + 0.044715f * v * v * v));
        vv[i] = 0.5f * v * (1.0f + t);
    }
    float4 r; r.x = vv[0]; r.y = vv[1]; r.z = vv[2]; r.w = vv[3];
    y0[i4] = r;
}

// ---------------------------------------------------------------------------
// Phase 5: out[b,o,l] = bias[o] + x[b,o,l] + sum_h W[o,h]*u[b,h,l] (unchanged)
// ---------------------------------------------------------------------------
__global__ __launch_bounds__(256)
void gemm_kernel(const float* __restrict__ u, const float* __restrict__ W,
                 const float* __restrict__ bias, const float* __restrict__ x,
                 float* __restrict__ out) {
    int l0 = blockIdx.x * 64;
    int o0 = blockIdx.y * 128;
    int b  = blockIdx.z;
    int tid = threadIdx.x;
    __shared__ float Ws[16][129];   // [k][o]
    __shared__ float Us[16][65];    // [k][l]
    const float* ub = u + (size_t)b * Hq * Lq;
    float acc[8][4] = {};
    int wo = tid >> 4, wl = tid & 15;
    for (int k0 = 0; k0 < Hq; k0 += 16) {
        {
            int j  = tid & 15;       // k
            int ib = tid >> 4;       // o base
            #pragma unroll
            for (int r = 0; r < 8; ++r) {
                int i = ib + 16 * r;
                Ws[j][i] = W[(size_t)(o0 + i) * Hq + k0 + j];
            }
            int li = tid & 63;
            int jb = tid >> 6;
            #pragma unroll
            for (int r = 0; r < 4; ++r) {
                int j2 = jb + 4 * r;
                Us[j2][li] = ub[(size_t)(k0 + j2) * Lq + l0 + li];
            }
        }
        __syncthreads();
        #pragma unroll
        for (int j = 0; j < 16; ++j) {
            float av[8], bv[4];
            #pragma unroll
            for (int i = 0; i < 8; ++i) av[i] = Ws[j][8 * wo + i];
            #pragma unroll
            for (int i = 0; i < 4; ++i) bv[i] = Us[j][4 * wl + i];
            #pragma unroll
            for (int io = 0; io < 8; ++io)
                #pragma unroll
                for (int il = 0; il < 4; ++il)
                    acc[io][il] = fmaf(av[io], bv[il], acc[io][il]);
        }
        __syncthreads();
    }
    #pragma unroll
    for (int io = 0; io < 8; ++io) {
        int o = o0 + 8 * wo + io;
        float bo = bias[o];
        size_t base = ((size_t)b * Hq + o) * Lq + l0 + 4 * wl;
        const float4 xr = *(const float4*)(x + base);
        float4 r;
        r.x = acc[io][0] + bo + xr.x;
        r.y = acc[io][1] + bo + xr.y;
        r.z = acc[io][2] + bo + xr.z;
        r.w = acc[io][3] + bo + xr.w;
        *(float4*)(out + base) = r;
    }
}

// ---------------------------------------------------------------------------
extern "C" void kernel_launch(void* const* d_in, const int* in_sizes, int n_in,
                              void* d_out, int out_size, void* d_ws, size_t ws_size,
                              hipStream_t stream) {
    (void)in_sizes; (void)n_in; (void)out_size; (void)ws_size;
    const float* x          = (const float*)d_in[0];
    const float* ln_w       = (const float*)d_in[1];
    const float* ln_b       = (const float*)d_in[2];
    const float* log_dt     = (const float*)d_in[3];
    const float* log_A_real = (const float*)d_in[4];
    const float* A_imag     = (const float*)d_in[5];
    const float* B_re       = (const float*)d_in[6];
    const float* B_im       = (const float*)d_in[7];
    const float* C_re       = (const float*)d_in[8];
    const float* C_im       = (const float*)d_in[9];
    const float* Dv         = (const float*)d_in[10];
    const float* W          = (const float*)d_in[11];
    const float* b_out      = (const float*)d_in[12];
    float* out = (float*)d_out;
    float* ws  = (float*)d_ws;

    const size_t BHL = (size_t)Bq * Hq * Lq;
    float* wr  = ws;
    float* wi  = ws + PARAM;
    float* a0  = ws + 2 * (size_t)PARAM;
    float* b0  = ws + 3 * (size_t)PARAM;
    float* a1  = ws + 4 * (size_t)PARAM;
    float* b1  = ws + 5 * (size_t)PARAM;
    float* wpr = ws + 6 * (size_t)PARAM;           // 3*PARAM
    float* wpi = ws + 9 * (size_t)PARAM;           // 3*PARAM
    float* z   = ws + 12 * (size_t)PARAM;          // B*H*L
    float* y0  = z  + BHL;                         // also holds u after act
    float* y1  = y0 + BHL;
    float* slc = y1 + BHL;                         // BH*2*(CCH-1)*128 floats

    prep_kernel<<<PARAM / 256, 256, 0, stream>>>(log_dt, log_A_real, A_imag,
                                                 B_re, B_im, C_re, C_im,
                                                 wr, wi, a0, b0, a1, b1, wpr, wpi);
    ln_kernel<<<Bq * (Lq / 16), 256, 0, stream>>>(x, ln_w, ln_b, z);
    local_kernel<<<dim3(BH / 4, 2, CCH - 1), 256, 0, stream>>>(z, wr, wi, slc);
    scan_kernel<<<dim3(BH, 2), 256, 0, stream>>>(z, wr, wi, a0, b0, a1, b1,
                                                 wpr, wpi, slc, y0, y1);
    act_kernel<<<(Bq * Hq * Lq / 4) / 256, 256, 0, stream>>>((float4*)y0, (const float4*)y1,
                                                             (const float4*)z, Dv);
    gemm_kernel<<<dim3(Lq / 64, Hq / 128, Bq), 256, 0, stream>>>(y0, W, b_out, x, out);
}

// Round 2
// 324.276 us; speedup vs baseline: 1.1521x; 1.1521x over previous
//
#include <hip/hip_runtime.h>
#include <math.h>

#define Bq 4
#define Hq 512
#define Nq 64
#define Lq 2048
#define PARAM (Hq*Nq)   // 32768
#define T 64
#define NC (Lq/T)       // 32 chunks
#define NCOL 256        // 2 dirs * Bq * NC columns per h

// ---------------------------------------------------------------------------
// Phase 1: per-(h,n) parameter prep.
//   w  = exp(dt*A);  dB = B*(w-1)/A;  CB = C*dB
//   store a = 2*Re(CB), b = -2*Im(CB) so y += a*sr + b*si
// ---------------------------------------------------------------------------
__global__ void prep_kernel(const float* __restrict__ log_dt,
                            const float* __restrict__ log_A_real,
                            const float* __restrict__ A_imag,
                            const float* __restrict__ B_re, const float* __restrict__ B_im,
                            const float* __restrict__ C_re, const float* __restrict__ C_im,
                            float* __restrict__ wr_, float* __restrict__ wi_,
                            float* __restrict__ a0, float* __restrict__ b0,
                            float* __restrict__ a1, float* __restrict__ b1) {
    int idx = blockIdx.x * blockDim.x + threadIdx.x;
    if (idx >= PARAM) return;
    int h = idx >> 6;
    float dt = expf(log_dt[h]);
    float Ar = -expf(log_A_real[idx]);
    float Ai = A_imag[idx];
    float er = expf(Ar * dt);
    float wr = er * cosf(Ai * dt);
    float wi = er * sinf(Ai * dt);
    wr_[idx] = wr; wi_[idx] = wi;
    float mr = wr - 1.0f, mi = wi;
    float den = Ar * Ar + Ai * Ai;
    float qr = (mr * Ar + mi * Ai) / den;
    float qi = (mi * Ar - mr * Ai) / den;
    float Br = B_re[idx], Bi = B_im[idx];
    float dBr = Br * qr - Bi * qi;
    float dBi = Br * qi + Bi * qr;
    float cr = C_re[idx], ci = C_im[idx];
    a0[idx] =  2.0f * (cr * dBr - ci * dBi);
    b0[idx] = -2.0f * (cr * dBi + ci * dBr);
    cr = C_re[PARAM + idx]; ci = C_im[PARAM + idx];
    a1[idx] =  2.0f * (cr * dBr - ci * dBi);
    b1[idx] = -2.0f * (cr * dBi + ci * dBr);
}

// ---------------------------------------------------------------------------
// Phase 2: LayerNorm over channel dim H for each (b,l).  (unchanged)
// ---------------------------------------------------------------------------
__global__ __launch_bounds__(256)
void ln_kernel(const float* __restrict__ x, const float* __restrict__ lnw,
               const float* __restrict__ lnb, float* __restrict__ z) {
    int blk = blockIdx.x;
    int b  = blk / (Lq / 16);
    int l0 = (blk % (Lq / 16)) * 16;
    int tx = threadIdx.x & 15;
    int ty = threadIdx.x >> 4;
    const float* xb = x + (size_t)b * Hq * Lq;
    float s = 0.f, s2 = 0.f;
    for (int h = ty; h < Hq; h += 16) {
        float v = xb[h * Lq + l0 + tx];
        s += v; s2 += v * v;
    }
    __shared__ float rs_[16][17], r2_[16][17], mu_s[16], sg_s[16];
    rs_[ty][tx] = s; r2_[ty][tx] = s2;
    __syncthreads();
    if (ty == 0) {
        float a = 0.f, c = 0.f;
        #pragma unroll
        for (int i = 0; i < 16; ++i) { a += rs_[i][tx]; c += r2_[i][tx]; }
        float mu = a * (1.0f / Hq);
        float var = c * (1.0f / Hq) - mu * mu;
        mu_s[tx] = mu;
        sg_s[tx] = rsqrtf(var + 1e-5f);
    }
    __syncthreads();
    float mu = mu_s[tx], rs = sg_s[tx];
    float* zb = z + (size_t)b * Hq * Lq;
    for (int h = ty; h < Hq; h += 16) {
        float v = xb[h * Lq + l0 + tx];
        zb[h * Lq + l0 + tx] = (v - mu) * rs * lnw[h] + lnb[h];
    }
}

// ---------------------------------------------------------------------------
// SSD decomposition. Scan-order index tau: dir0 -> z[tau], dir1 -> z[L-1-tau].
// Chunk c covers tau in [c*64, c*64+64).  zhat[c,j] = z[scan(c*64+j)].
//   s after chunk = w^64 * s_init + delta,  delta[n] = sum_j w^(63-j) zhat[j]
//   dir0 (update-then-output): y[c,i] = sum_n 2Re(CB w^(i+1) s_init)
//                                      + sum_{j<=i} k[i-j] zhat[j]
//   dir1 (output-then-update): y[c,i] = sum_n 2Re(CB w^i s_init)
//                                      + sum_{j<i} k[i-1-j] zhat[j]
//   k[d] = sum_n (a_n Re(w^d) + b_n (-Im... folded: a*c + b*s with our a,b)
// Column index everywhere: col = dir*128 + b*32 + c.
// ---------------------------------------------------------------------------

// delta GEMM: per (h, colTile of 64): rows 2n(re)/2n+1(im) = 128, K=64.
// buf[((h*256+col)*128) + row] = delta.
__global__ __launch_bounds__(256)
void delta_kernel(const float* __restrict__ z,
                  const float* __restrict__ wr_, const float* __restrict__ wi_,
                  float* __restrict__ buf) {
    __shared__ float powc[64][64], pows[64][64];   // w^d, d=0..63
    __shared__ float Bs[64][68];                   // zhat [col][j]
    int h = blockIdx.x, ct = blockIdx.y;           // ct: dir=ct>>1, b-half=ct&1
    int t = threadIdx.x;
    if (t < 64) {                                  // wave 0 builds power table
        float wr = wr_[h*64+t], wi = wi_[h*64+t];
        float c = 1.f, s = 0.f;
        for (int d = 0; d < 64; ++d) {
            powc[d][t] = c; pows[d][t] = s;
            float nc = c*wr - s*wi, ns = c*wi + s*wr;
            c = nc; s = ns;
        }
    }
    {   // stage zhat: two contiguous 8KB runs (b-halves)
        int dir = ct >> 1;
        int r = t >> 7, tt = t & 127;
        int b = (ct & 1)*2 + r;
        int l = tt * 16;
        int c0 = l >> 6, j0 = l & 63;
        const float* zb = z + ((size_t)b*Hq + h)*Lq;
        int cc = r*32 + c0;
        if (dir == 0) {
            #pragma unroll
            for (int q = 0; q < 4; ++q)
                *(float4*)&Bs[cc][j0+4*q] = *(const float4*)(zb + c0*64 + j0 + 4*q);
        } else {
            #pragma unroll
            for (int q = 0; q < 4; ++q) {
                float4 v = *(const float4*)(zb + 2044 - c0*64 - (j0+4*q));
                float4 w; w.x = v.w; w.y = v.z; w.z = v.y; w.w = v.x;
                *(float4*)&Bs[cc][j0+4*q] = w;
            }
        }
    }
    __syncthreads();
    int cg = t & 15, rg = t >> 4;        // cols: cg+16q (bank-spread); n0=4*rg
    int n0 = 4*rg;
    float aR[4][4] = {}, aI[4][4] = {};
    #pragma unroll 4
    for (int j = 0; j < 64; ++j) {
        int d = 63 - j;
        float4 pc = *(const float4*)&powc[d][n0];
        float4 ps = *(const float4*)&pows[d][n0];
        float bz[4];
        #pragma unroll
        for (int q = 0; q < 4; ++q) bz[q] = Bs[cg + 16*q][j];
        #pragma unroll
        for (int nn = 0; nn < 4; ++nn) {
            float pcv = (&pc.x)[nn], psv = (&ps.x)[nn];
            #pragma unroll
            for (int q = 0; q < 4; ++q) {
                aR[nn][q] = fmaf(pcv, bz[q], aR[nn][q]);
                aI[nn][q] = fmaf(psv, bz[q], aI[nn][q]);
            }
        }
    }
    #pragma unroll
    for (int q = 0; q < 4; ++q) {
        int col = ct*64 + cg + 16*q;
        float* dst = buf + ((size_t)h*NCOL + col)*128 + 2*n0;
        float4 v1, v2;
        v1.x = aR[0][q]; v1.y = aI[0][q]; v1.z = aR[1][q]; v1.w = aI[1][q];
        v2.x = aR[2][q]; v2.y = aI[2][q]; v2.z = aR[3][q]; v2.w = aI[3][q];
        *(float4*)dst = v1; *(float4*)(dst+4) = v2;
    }
}

// inter-chunk scan, in place: reads delta[c], writes s_init[c] (pre-state).
__global__ __launch_bounds__(256)
void cscan_kernel(const float* __restrict__ wr_, const float* __restrict__ wi_,
                  float* __restrict__ buf) {
    int e = blockIdx.x*4 + (threadIdx.x >> 6);     // 0..4095
    int n = threadIdx.x & 63;
    int h = e >> 3, dir = (e >> 2) & 1, b = e & 3;
    float wr = wr_[h*64+n], wi = wi_[h*64+n];
    double cr = wr, ci = wi;                        // w^64 via 6 squarings
    #pragma unroll
    for (int q = 0; q < 6; ++q) {
        double nr = cr*cr - ci*ci, ni = 2.0*cr*ci;
        cr = nr; ci = ni;
    }
    float tc = (float)cr, ts = (float)ci;
    float sr = 0.f, si = 0.f;
    float2* p = (float2*)(buf + ((size_t)h*NCOL + dir*128 + b*32)*128) + n;
    float2 d = p[0];
    for (int c = 0; c < NC; ++c) {
        float2 dn;
        if (c + 1 < NC) dn = p[(c+1)*64];
        float2 s; s.x = sr; s.y = si;
        p[c*64] = s;                                // pre-state for chunk c
        float nr = fmaf(tc, sr, fmaf(-ts, si, d.x));
        float ni = fmaf(ts, sr, fmaf(tc, si, d.y));
        sr = nr; si = ni; d = dn;
    }
}

// Y GEMM: per (h, dir, colTile of 64): Y[i,col] = K@zhat + G@S, M=64, K=192.
__global__ __launch_bounds__(256)
void y_kernel(const float* __restrict__ z,
              const float* __restrict__ wr_, const float* __restrict__ wi_,
              const float* __restrict__ a0, const float* __restrict__ b0,
              const float* __restrict__ a1, const float* __restrict__ b1,
              const float* __restrict__ buf,
              float* __restrict__ y0, float* __restrict__ y1) {
    __shared__ float powc[64][64], pows[64][64];   // rows: d = i + (dir0?1:0)
    __shared__ float As[32][64];
    __shared__ float Bs[64][36];
    __shared__ float ks[64], as_[64], bs_[64];
    int h = blockIdx.x, dir = blockIdx.y, ct = blockIdx.z;
    int t = threadIdx.x;
    const float* aa = dir ? a1 : a0;
    const float* bb = dir ? b1 : b0;
    if (t < 64) {
        float wr = wr_[h*64+t], wi = wi_[h*64+t];
        as_[t] = aa[h*64+t]; bs_[t] = bb[h*64+t];
        float c, s;
        if (dir == 0) { c = wr; s = wi; } else { c = 1.f; s = 0.f; }
        for (int d = 0; d < 64; ++d) {
            powc[d][t] = c; pows[d][t] = s;
            float nc = c*wr - s*wi, ns = c*wi + s*wr;
            c = nc; s = ns;
        }
    }
    __syncthreads();
    if (t < 64) {                                  // k[d], skewed n to avoid bank hits
        int d = t;
        float acc = 0.f;
        if (dir == 0 && d == 0) {
            for (int st = 0; st < 64; ++st) acc += as_[(st + d) & 63];
        } else {
            int row = (dir == 0) ? d - 1 : d;
            for (int st = 0; st < 64; ++st) {
                int n = (st + d) & 63;
                acc = fmaf(as_[n], powc[row][n], acc);
                acc = fmaf(bs_[n], pows[row][n], acc);
            }
        }
        ks[d] = acc;
    }
    __syncthreads();
    int tx = t & 15, ty = t >> 4;
    float acc[4][4] = {};
    for (int p = 0; p < 6; ++p) {
        {   // stage A rows (k-tile of 32)
            int kk = t & 31, ig = t >> 5;
            if (p < 2) {                            // Toeplitz K rows j
                int j = 32*p + kk;
                int off = (dir == 0) ? 0 : 1;
                #pragma unroll
                for (int ii = 0; ii < 8; ++ii) {
                    int i = ig*8 + ii;
                    int idx = i - j - off;
                    As[kk][i] = (idx >= 0) ? ks[idx] : 0.f;
                }
            } else {                                // G rows m
                int m = 32*(p-2) + kk;
                int n = m >> 1;
                float av = as_[n], bv = bs_[n];
                if ((m & 1) == 0) {
                    #pragma unroll
                    for (int ii = 0; ii < 8; ++ii) {
                        int i = ig*8 + ii;
                        As[kk][i] = fmaf(av, powc[i][n], bv*pows[i][n]);
                    }
                } else {
                    #pragma unroll
                    for (int ii = 0; ii < 8; ++ii) {
                        int i = ig*8 + ii;
                        As[kk][i] = fmaf(bv, powc[i][n], -av*pows[i][n]);
                    }
                }
            }
        }
        {   // stage B: zhat (p<2) or S rows (p>=2)
            int cc = t >> 2, q = t & 3;
            int colg = ct*64 + cc;                  // b*32+c
            int b = colg >> 5, c = colg & 31;
            int kk0 = q*8;
            if (p < 2) {
                const float* zb = z + ((size_t)b*Hq + h)*Lq;
                int j0 = 32*p + kk0;
                if (dir == 0) {
                    *(float4*)&Bs[cc][kk0]   = *(const float4*)(zb + c*64 + j0);
                    *(float4*)&Bs[cc][kk0+4] = *(const float4*)(zb + c*64 + j0 + 4);
                } else {
                    float4 v = *(const float4*)(zb + 2044 - c*64 - j0);
                    float4 w; w.x=v.w; w.y=v.z; w.z=v.y; w.w=v.x;
                    *(float4*)&Bs[cc][kk0] = w;
                    v = *(const float4*)(zb + 2044 - c*64 - (j0+4));
                    w.x=v.w; w.y=v.z; w.z=v.y; w.w=v.x;
                    *(float4*)&Bs[cc][kk0+4] = w;
                }
            } else {
                int m0 = 32*(p-2) + kk0;
                int col = dir*128 + colg;
                const float* src = buf + ((size_t)h*NCOL + col)*128 + m0;
                *(float4*)&Bs[cc][kk0]   = *(const float4*)src;
                *(float4*)&Bs[cc][kk0+4] = *(const float4*)(src+4);
            }
        }
        __syncthreads();
        #pragma unroll 8
        for (int kk = 0; kk < 32; ++kk) {
            float4 av = *(const float4*)&As[kk][4*tx];
            float bv0 = Bs[4*ty+0][kk], bv1 = Bs[4*ty+1][kk];
            float bv2 = Bs[4*ty+2][kk], bv3 = Bs[4*ty+3][kk];
            #pragma unroll
            for (int ii = 0; ii < 4; ++ii) {
                float a = (&av.x)[ii];
                acc[ii][0] = fmaf(a, bv0, acc[ii][0]);
                acc[ii][1] = fmaf(a, bv1, acc[ii][1]);
                acc[ii][2] = fmaf(a, bv2, acc[ii][2]);
                acc[ii][3] = fmaf(a, bv3, acc[ii][3]);
            }
        }
        __syncthreads();
    }
    #pragma unroll
    for (int q = 0; q < 4; ++q) {
        int colg = ct*64 + 4*ty + q;
        int b = colg >> 5, c = colg & 31;
        float4 v;
        if (dir == 0) {
            v.x = acc[0][q]; v.y = acc[1][q]; v.z = acc[2][q]; v.w = acc[3][q];
            *(float4*)(y0 + ((size_t)b*Hq + h)*Lq + c*64 + 4*tx) = v;
        } else {
            v.x = acc[3][q]; v.y = acc[2][q]; v.z = acc[1][q]; v.w = acc[0][q];
            *(float4*)(y1 + ((size_t)b*Hq + h)*Lq + 2044 - c*64 - 4*tx) = v;
        }
    }
}

// ---------------------------------------------------------------------------
// Phase 4: u = gelu_tanh(y0 + y1 + D*z), in-place into y0. (unchanged)
// ---------------------------------------------------------------------------
__global__ __launch_bounds__(256)
void act_kernel(float4* __restrict__ y0, const float4* __restrict__ y1,
                const float4* __restrict__ z, const float* __restrict__ D) {
    int i4 = blockIdx.x * 256 + threadIdx.x;
    int h = (i4 >> 9) & (Hq - 1);
    float d = D[h];
    float4 v0 = y0[i4], v1 = y1[i4], vz = z[i4];
    float vv[4] = { v0.x + v1.x + d * vz.x, v0.y + v1.y + d * vz.y,
                    v0.z + v1.z + d * vz.z, v0.w + v1.w + d * vz.w };
    #pragma unroll
    for (int i = 0; i < 4; ++i) {
        float v = vv[i];
        float tt = tanhf(0.7978845608028654f * (v + 0.044715f * v * v * v));
        vv[i] = 0.5f * v * (1.0f + tt);
    }
    float4 r; r.x = vv[0]; r.y = vv[1]; r.z = vv[2]; r.w = vv[3];
    y0[i4] = r;
}

// ---------------------------------------------------------------------------
// Phase 5: out = bias + x + W@u. (unchanged)
// ---------------------------------------------------------------------------
__global__ __launch_bounds__(256)
void gemm_kernel(const float* __restrict__ u, const float* __restrict__ W,
                 const float* __restrict__ bias, const float* __restrict__ x,
                 float* __restrict__ out) {
    int l0 = blockIdx.x * 64;
    int o0 = blockIdx.y * 128;
    int b  = blockIdx.z;
    int tid = threadIdx.x;
    __shared__ float Ws[16][129];
    __shared__ float Us[16][65];
    const float* ub = u + (size_t)b * Hq * Lq;
    float acc[8][4] = {};
    int wo = tid >> 4, wl = tid & 15;
    for (int k0 = 0; k0 < Hq; k0 += 16) {
        {
            int j  = tid & 15;
            int ib = tid >> 4;
            #pragma unroll
            for (int r = 0; r < 8; ++r) {
                int i = ib + 16 * r;
                Ws[j][i] = W[(size_t)(o0 + i) * Hq + k0 + j];
            }
            int li = tid & 63;
            int jb = tid >> 6;
            #pragma unroll
            for (int r = 0; r < 4; ++r) {
                int j2 = jb + 4 * r;
                Us[j2][li] = ub[(size_t)(k0 + j2) * Lq + l0 + li];
            }
        }
        __syncthreads();
        #pragma unroll
        for (int j = 0; j < 16; ++j) {
            float av[8], bv[4];
            #pragma unroll
            for (int i = 0; i < 8; ++i) av[i] = Ws[j][8 * wo + i];
            #pragma unroll
            for (int i = 0; i < 4; ++i) bv[i] = Us[j][4 * wl + i];
            #pragma unroll
            for (int io = 0; io < 8; ++io)
                #pragma unroll
                for (int il = 0; il < 4; ++il)
                    acc[io][il] = fmaf(av[io], bv[il], acc[io][il]);
        }
        __syncthreads();
    }
    #pragma unroll
    for (int io = 0; io < 8; ++io) {
        int o = o0 + 8 * wo + io;
        float bo = bias[o];
        size_t base = ((size_t)b * Hq + o) * Lq + l0 + 4 * wl;
        const float4 xr = *(const float4*)(x + base);
        float4 r;
        r.x = acc[io][0] + bo + xr.x;
        r.y = acc[io][1] + bo + xr.y;
        r.z = acc[io][2] + bo + xr.z;
        r.w = acc[io][3] + bo + xr.w;
        *(float4*)(out + base) = r;
    }
}

// ---------------------------------------------------------------------------
extern "C" void kernel_launch(void* const* d_in, const int* in_sizes, int n_in,
                              void* d_out, int out_size, void* d_ws, size_t ws_size,
                              hipStream_t stream) {
    (void)in_sizes; (void)n_in; (void)out_size; (void)ws_size;
    const float* x          = (const float*)d_in[0];
    const float* ln_w       = (const float*)d_in[1];
    const float* ln_b       = (const float*)d_in[2];
    const float* log_dt     = (const float*)d_in[3];
    const float* log_A_real = (const float*)d_in[4];
    const float* A_imag     = (const float*)d_in[5];
    const float* B_re       = (const float*)d_in[6];
    const float* B_im       = (const float*)d_in[7];
    const float* C_re       = (const float*)d_in[8];
    const float* C_im       = (const float*)d_in[9];
    const float* Dv         = (const float*)d_in[10];
    const float* W          = (const float*)d_in[11];
    const float* b_out      = (const float*)d_in[12];
    float* out = (float*)d_out;
    float* ws  = (float*)d_ws;

    const size_t BHL = (size_t)Bq * Hq * Lq;
    float* wr  = ws;
    float* wi  = ws + PARAM;
    float* a0  = ws + 2 * (size_t)PARAM;
    float* b0  = ws + 3 * (size_t)PARAM;
    float* a1  = ws + 4 * (size_t)PARAM;
    float* b1  = ws + 5 * (size_t)PARAM;
    float* z   = ws + 6 * (size_t)PARAM;
    float* y0  = z  + BHL;
    float* y1  = y0 + BHL;
    float* buf = y1 + BHL;                 // 512*256*128 floats = 67 MB

    prep_kernel<<<PARAM / 256, 256, 0, stream>>>(log_dt, log_A_real, A_imag,
                                                 B_re, B_im, C_re, C_im,
                                                 wr, wi, a0, b0, a1, b1);
    ln_kernel<<<Bq * (Lq / 16), 256, 0, stream>>>(x, ln_w, ln_b, z);
    delta_kernel<<<dim3(Hq, 4), 256, 0, stream>>>(z, wr, wi, buf);
    cscan_kernel<<<Bq * Hq * 2 / 4, 256, 0, stream>>>(wr, wi, buf);
    y_kernel<<<dim3(Hq, 2, 2), 256, 0, stream>>>(z, wr, wi, a0, b0, a1, b1,
                                                 buf, y0, y1);
    act_kernel<<<(Bq * Hq * Lq / 4) / 256, 256, 0, stream>>>((float4*)y0, (const float4*)y1,
                                                             (const float4*)z, Dv);
    gemm_kernel<<<dim3(Lq / 64, Hq / 128, Bq), 256, 0, stream>>>(y0, W, b_out, x, out);
}